// Round 2
// baseline (5059.182 us; speedup 1.0000x reference)
//
#include <hip/hip_runtime.h>
#include <hip/hip_cooperative_groups.h>
#include <cmath>

namespace cg = cooperative_groups;

// B=256, T=48, N2=16, E=64, H=128, G=4H=512
// LDS layout (floats): sW [64][132] = 8448 | scratch 17408 (sX [256][68] etc.)
#define SW_FLOATS   8448
#define SCR_FLOATS  17408
#define SMEM_BYTES  ((SW_FLOATS + SCR_FLOATS) * 4)

__device__ __forceinline__ float sigf(float x){ return 1.0f/(1.0f+expf(-x)); }

__global__ __launch_bounds__(512, 2) void k_fused(
    const float* __restrict__ x, const float* __restrict__ Wd, const float* __restrict__ bd,
    const float* __restrict__ Ws, const float* __restrict__ bs,
    const float* __restrict__ W_ih, const float* __restrict__ b_ih,
    const float* __restrict__ W_hh, const float* __restrict__ b_hh,
    const float* __restrict__ W_ho, const float* __restrict__ b_ho,
    const float* __restrict__ W_out, const float* __restrict__ b_out,
    float* __restrict__ y,
    float* __restrict__ emb2, float* __restrict__ hst, float* __restrict__ cst,
    float* __restrict__ sbuf0, float* __restrict__ sbuf1, float* __restrict__ gates)
{
  extern __shared__ float smem[];
  float* sW = smem;                  // persistent gate weights [64][132]
  float* scratch = smem + SW_FLOATS; // 17408 floats

  const int bid = blockIdx.x;
  const int tid = threadIdx.x;
  cg::grid_group grid = cg::this_grid();

  const int n  = bid >> 4;           // node for G and C roles
  const int gc = bid & 15;           // gate-chunk (G role) / batch-tile (C role)
  const int gq = tid & 7, bq = tid >> 3;

  // ---- prologue: persistent weight slice (W_ih rows 0..31, W_hh rows 32..63) ----
  #pragma unroll
  for (int j = 0; j < 4; ++j) {
    int idx4 = (j*512 + tid)*4;      // 8192 floats
    int r = idx4 >> 7, k = idx4 & 127;
    const float* src = (r < 32) ? W_ih : W_hh;
    int g = r & 31;
    *(float4*)&sW[r*132 + k] = *(const float4*)&src[((size_t)n*512 + gc*32 + g)*128 + k];
  }
  float bias[4];
  #pragma unroll
  for (int i = 0; i < 4; ++i) {
    int gg = n*512 + gc*32 + gq + 8*i;
    bias[i] = b_ih[gg] + b_hh[gg];
  }
  // zero recurrent state; init social buffer 0 with bs
  #pragma unroll
  for (int j = 0; j < 4; ++j) {
    hst[(size_t)bid*2048 + j*512 + tid] = 0.f;
    cst[(size_t)bid*2048 + j*512 + tid] = 0.f;
  }
  if (tid < 64) sbuf0[bid*64 + tid] = bs[tid];

  // ---- downsample + embed: batch b = bid, all t ----
  {
    float* dsum = scratch, *dmax = scratch+512, *dmin = scratch+1024;
    float* cm = scratch+1536, *cx = scratch+1552, *cnn = scratch+1568;
    const int r = tid >> 3, c0 = (tid & 7) * 8;
    const int cell_w = (r >> 4)*4 + (c0 >> 4);
    const int slot = (r & 15)*2 + ((c0 >> 3) & 1);
    for (int t = 0; t < 48; ++t) {
      const float* xp = x + ((size_t)bid*48 + t)*4096 + r*64 + c0;
      float4 a = *(const float4*)xp;
      float4 b4 = *(const float4*)(xp+4);
      float sm = a.x+a.y+a.z+a.w + b4.x+b4.y+b4.z+b4.w;
      float mx = fmaxf(fmaxf(fmaxf(a.x,a.y),fmaxf(a.z,a.w)), fmaxf(fmaxf(b4.x,b4.y),fmaxf(b4.z,b4.w)));
      float mn = fminf(fminf(fminf(a.x,a.y),fminf(a.z,a.w)), fminf(fminf(b4.x,b4.y),fminf(b4.z,b4.w)));
      dsum[cell_w*32+slot] = sm; dmax[cell_w*32+slot] = mx; dmin[cell_w*32+slot] = mn;
      __syncthreads();
      if (tid < 256) {
        int cell = tid >> 4, l = tid & 15;
        float s2 = dsum[cell*32+l] + dsum[cell*32+l+16];
        float m2 = fmaxf(dmax[cell*32+l], dmax[cell*32+l+16]);
        float n2 = fminf(dmin[cell*32+l], dmin[cell*32+l+16]);
        #pragma unroll
        for (int m = 8; m >= 1; m >>= 1) {
          s2 += __shfl_xor(s2, m, 16);
          m2 = fmaxf(m2, __shfl_xor(m2, m, 16));
          n2 = fminf(n2, __shfl_xor(n2, m, 16));
        }
        if (l == 0) { cm[cell] = s2*(1.f/256.f); cx[cell] = m2; cnn[cell] = n2; }
      }
      __syncthreads();
      #pragma unroll
      for (int j = 0; j < 2; ++j) {
        int idx = j*512 + tid;
        int cell = idx >> 6, e = idx & 63;
        float v = cm[cell]*Wd[e] + cx[cell]*Wd[64+e] + cnn[cell]*Wd[128+e] + bd[e];
        emb2[(((size_t)t*16 + cell)*256 + bid)*64 + e] = fmaxf(v, 0.f);
      }
      __syncthreads();
    }
  }
  grid.sync();

  const float4* sW4 = (const float4*)sW;
  float* sX  = scratch;              // [256][68] during G
  const float4* sX4 = (const float4*)scratch;
  const int b0c = gc * 16;           // C-role batch base
  float* sH  = scratch;              // [16][132]
  float* sWs = scratch + 2112;       // [128][68]
  float* red = scratch + 10816;      // [16][132]

  for (int t = 0; t < 48; ++t) {
    const int cur = t & 1;
    const float* sbC = cur ? sbuf1 : sbuf0;
    float*       sbN = cur ? sbuf0 : sbuf1;

    // ================= G phase: gates for (n, gc), all 256 b =================
    if (tid < 64) sbN[bid*64 + tid] = bs[tid];   // init next social accum = bs
    float acc[4][4];
    #pragma unroll
    for (int i=0;i<4;++i){ acc[i][0]=0.f; acc[i][1]=0.f; acc[i][2]=0.f; acc[i][3]=0.f; }

    for (int kc = 0; kc < 4; ++kc) {             // k-chunks of 64 (x,e | social | h_lo | h_hi)
      __syncthreads();
      #pragma unroll
      for (int j = 0; j < 8; ++j) {              // stage sX[256][68]
        int idx4 = (j*512 + tid)*4;
        int bb = idx4 >> 6, kk = idx4 & 63;
        float4 v;
        if (kc == 0)      v = *(const float4*)&emb2[(((size_t)t*16 + n)*256 + bb)*64 + kk];
        else if (kc == 1) { v = *(const float4*)&sbC[bb*64 + kk];
                            v.x=fmaxf(v.x,0.f); v.y=fmaxf(v.y,0.f); v.z=fmaxf(v.z,0.f); v.w=fmaxf(v.w,0.f); }
        else              v = *(const float4*)&hst[((size_t)bb*16 + n)*128 + (kc-2)*64 + kk];
        *(float4*)&sX[bb*68 + kk] = v;
      }
      __syncthreads();
      const int wbase = (kc >= 2) ? 32 : 0;
      const int wcol  = (kc & 1) * 16;
      #pragma unroll 4
      for (int k4 = 0; k4 < 16; ++k4) {
        float4 wv[4], xv[4];
        #pragma unroll
        for (int i = 0; i < 4; ++i) wv[i] = sW4[(wbase + gq + 8*i)*33 + wcol + k4];
        #pragma unroll
        for (int j = 0; j < 4; ++j) xv[j] = sX4[(bq + 64*j)*17 + k4];
        #pragma unroll
        for (int i = 0; i < 4; ++i)
          #pragma unroll
          for (int j = 0; j < 4; ++j) {
            acc[i][j] = fmaf(wv[i].x, xv[j].x, acc[i][j]);
            acc[i][j] = fmaf(wv[i].y, xv[j].y, acc[i][j]);
            acc[i][j] = fmaf(wv[i].z, xv[j].z, acc[i][j]);
            acc[i][j] = fmaf(wv[i].w, xv[j].w, acc[i][j]);
          }
      }
    }
    #pragma unroll
    for (int i = 0; i < 4; ++i)
      #pragma unroll
      for (int j = 0; j < 4; ++j)
        gates[(((size_t)(bq + 64*j))*16 + n)*512 + gc*32 + gq + 8*i] = acc[i][j] + bias[i];
    grid.sync();

    // ================= C phase: cell+social+head for (n, b0c..b0c+15) =================
    #pragma unroll
    for (int j = 0; j < 4; ++j) {                // stage Ws[n] -> sWs[128][68]
      int idx4 = (j*512 + tid)*4;
      int h = idx4 >> 6, e = idx4 & 63;
      *(float4*)&sWs[h*68 + e] = *(const float4*)&Ws[(((size_t)n*128 + h)<<6) + e];
    }
    { // LSTM cell: 2048 cells, float4 per thread
      int idx4 = tid*4;
      int bb = idx4 >> 7, hh = idx4 & 127;
      size_t gbase = (((size_t)(b0c+bb))*16 + n)*512 + hh;
      float4 iv = *(const float4*)&gates[gbase];
      float4 fv = *(const float4*)&gates[gbase+128];
      float4 gv = *(const float4*)&gates[gbase+256];
      float4 ov = *(const float4*)&gates[gbase+384];
      size_t saddr = (((size_t)(b0c+bb))*16 + n)*128 + hh;
      float4 cv = *(const float4*)&cst[saddr];
      float4 cn4, hn4;
      cn4.x = sigf(fv.x)*cv.x + sigf(iv.x)*tanhf(gv.x);
      cn4.y = sigf(fv.y)*cv.y + sigf(iv.y)*tanhf(gv.y);
      cn4.z = sigf(fv.z)*cv.z + sigf(iv.z)*tanhf(gv.z);
      cn4.w = sigf(fv.w)*cv.w + sigf(iv.w)*tanhf(gv.w);
      hn4.x = sigf(ov.x)*tanhf(cn4.x);
      hn4.y = sigf(ov.y)*tanhf(cn4.y);
      hn4.z = sigf(ov.z)*tanhf(cn4.z);
      hn4.w = sigf(ov.w)*tanhf(cn4.w);
      *(float4*)&cst[saddr] = cn4;
      *(float4*)&hst[saddr] = hn4;
      *(float4*)&sH[bb*132 + hh] = hn4;
    }
    __syncthreads();
    { // social projection -> atomic accumulate into next social buffer
      const int b = tid >> 5, e0 = (tid & 31)*2;
      float a0 = 0.f, a1 = 0.f;
      #pragma unroll 4
      for (int h = 0; h < 128; h += 4) {
        float4 hv = *(const float4*)&sH[b*132 + h];
        float2 wA = *(const float2*)&sWs[(h+0)*68 + e0];
        float2 wB = *(const float2*)&sWs[(h+1)*68 + e0];
        float2 wC = *(const float2*)&sWs[(h+2)*68 + e0];
        float2 wD = *(const float2*)&sWs[(h+3)*68 + e0];
        a0 = fmaf(hv.x,wA.x, fmaf(hv.y,wB.x, fmaf(hv.z,wC.x, fmaf(hv.w,wD.x, a0))));
        a1 = fmaf(hv.x,wA.y, fmaf(hv.y,wB.y, fmaf(hv.z,wC.y, fmaf(hv.w,wD.y, a1))));
      }
      atomicAdd(&sbN[(b0c + b)*64 + e0],     a0);
      atomicAdd(&sbN[(b0c + b)*64 + e0 + 1], a1);
    }
    { // output head: pre[b][o], 4 b's per thread
      const int o = tid & 127, bh = tid >> 7;
      float a4[4] = {0.f,0.f,0.f,0.f};
      const float* wp = W_ho + (size_t)n*16384 + o;
      #pragma unroll 4
      for (int h = 0; h < 128; h += 4) {
        float4 w4;
        w4.x = wp[(size_t)(h+0)*128]; w4.y = wp[(size_t)(h+1)*128];
        w4.z = wp[(size_t)(h+2)*128]; w4.w = wp[(size_t)(h+3)*128];
        #pragma unroll
        for (int j = 0; j < 4; ++j) {
          float4 hv = *(const float4*)&sH[(bh*4+j)*132 + h];
          a4[j] = fmaf(hv.x,w4.x, fmaf(hv.y,w4.y, fmaf(hv.z,w4.z, fmaf(hv.w,w4.w, a4[j]))));
        }
      }
      float bho = b_ho[n*128 + o], wo = W_out[o];
      #pragma unroll
      for (int j = 0; j < 4; ++j)
        red[(bh*4 + j)*132 + o] = wo * sigf(a4[j] + bho);
    }
    __syncthreads();
    if (tid < 256) { // reduce over o -> y
      int bb = tid >> 4, l = tid & 15;
      float sm = 0.f;
      #pragma unroll
      for (int k = 0; k < 8; ++k) sm += red[bb*132 + l + 16*k];
      #pragma unroll
      for (int m = 8; m >= 1; m >>= 1) sm += __shfl_xor(sm, m, 16);
      if (l == 0) y[(((size_t)t*256) + b0c + bb)*16 + n] = sm + b_out[0];
    }
    grid.sync();
  }
}

extern "C" void kernel_launch(void* const* d_in, const int* in_sizes, int n_in,
                              void* d_out, int out_size, void* d_ws, size_t ws_size,
                              hipStream_t stream){
  const float* x    = (const float*)d_in[0];
  const float* Wd   = (const float*)d_in[1];
  const float* bd   = (const float*)d_in[2];
  const float* Ws   = (const float*)d_in[3];
  const float* bs   = (const float*)d_in[4];
  const float* W_ih = (const float*)d_in[5];
  const float* b_ih = (const float*)d_in[6];
  const float* W_hh = (const float*)d_in[7];
  const float* b_hh = (const float*)d_in[8];
  const float* W_ho = (const float*)d_in[9];
  const float* b_ho = (const float*)d_in[10];
  const float* W_out= (const float*)d_in[11];
  const float* b_out= (const float*)d_in[12];
  float* y = (float*)d_out;

  float* ws = (float*)d_ws;
  float* emb2  = ws;                                  // 12,582,912
  float* hst   = emb2 + (size_t)256*48*16*64;         // 524,288
  float* cst   = hst + (size_t)256*16*128;            // 524,288
  float* sbuf0 = cst + (size_t)256*16*128;            // 16,384
  float* sbuf1 = sbuf0 + (size_t)256*64;              // 16,384
  float* gates = sbuf1 + (size_t)256*64;              // 2,097,152

  hipFuncSetAttribute((const void*)k_fused, hipFuncAttributeMaxDynamicSharedMemorySize, SMEM_BYTES);

  void* args[] = { (void*)&x, (void*)&Wd, (void*)&bd, (void*)&Ws, (void*)&bs,
                   (void*)&W_ih, (void*)&b_ih, (void*)&W_hh, (void*)&b_hh,
                   (void*)&W_ho, (void*)&b_ho, (void*)&W_out, (void*)&b_out,
                   (void*)&y, (void*)&emb2, (void*)&hst, (void*)&cst,
                   (void*)&sbuf0, (void*)&sbuf1, (void*)&gates };
  hipLaunchCooperativeKernel((const void*)k_fused, dim3(256), dim3(512), args, SMEM_BYTES, stream);
}

// Round 3
// 3653.474 us; speedup vs baseline: 1.3848x; 1.3848x over previous
//
#include <hip/hip_runtime.h>
#include <hip/hip_cooperative_groups.h>
#include <cmath>

namespace cg = cooperative_groups;

// B=256, T=48, N2=16, E=64, H=128, G=4H=512
// Block = (node n, batch-tile bt of 16 batches). h/c state persistent in LDS.
// Gates GEMM: thread = (h = tid>>2, bq = tid&3); acc float4 = 4 gate types.
// Weights pre-transposed: Wt2[n][k][h][i] (i = gate type), k 0..127 = x (emb|social), 128..255 = h.

__device__ __forceinline__ float sigf(float x){ return 1.0f/(1.0f+expf(-x)); }
__device__ __forceinline__ void fma4(float4& a, const float4 w, const float s){
  a.x = fmaf(w.x, s, a.x); a.y = fmaf(w.y, s, a.y);
  a.z = fmaf(w.z, s, a.z); a.w = fmaf(w.w, s, a.w);
}

__global__ __launch_bounds__(512, 2) void k_fused(
    const float* __restrict__ x, const float* __restrict__ Wd, const float* __restrict__ bd,
    const float* __restrict__ Ws, const float* __restrict__ bs,
    const float* __restrict__ W_ih, const float* __restrict__ b_ih,
    const float* __restrict__ W_hh, const float* __restrict__ b_hh,
    const float* __restrict__ W_ho, const float* __restrict__ b_ho,
    const float* __restrict__ W_out, const float* __restrict__ b_out,
    float* __restrict__ y,
    float* __restrict__ emb2, float* __restrict__ Wt2, float* __restrict__ WsT,
    float* __restrict__ W_hoT, float* __restrict__ bsum2,
    float* __restrict__ psoc, int* __restrict__ flag)
{
  __shared__ float sX[16*260];   // [b][k 0..255] staged GEMM input (pad 260)
  __shared__ float sH[16*132];   // persistent h state
  __shared__ float sC[16*132];   // persistent c state
  __shared__ float red[16*132];  // head partials for y-reduce

  const int bid = blockIdx.x, tid = threadIdx.x;
  cg::grid_group grid = cg::this_grid();

  for (int j = tid; j < 16*132; j += 512) { sH[j] = 0.f; sC[j] = 0.f; }
  if (bid == 0) for (int j = tid; j < 16*48; j += 512) flag[j] = 0;

  // ---------- prologue A: downsample + embed for batch b = bid ----------
  {
    float* dsum = sX; float* dmax = sX+512; float* dmin = sX+1024;
    float* cm = sX+1536; float* cx = sX+1552; float* cnn = sX+1568;
    const int r = tid >> 3, c0 = (tid & 7) * 8;
    const int cell_w = (r >> 4)*4 + (c0 >> 4);
    const int slot = (r & 15)*2 + ((c0 >> 3) & 1);
    for (int t = 0; t < 48; ++t) {
      const float* xp = x + ((size_t)bid*48 + t)*4096 + r*64 + c0;
      float4 a = *(const float4*)xp;
      float4 b4 = *(const float4*)(xp+4);
      float sm = a.x+a.y+a.z+a.w + b4.x+b4.y+b4.z+b4.w;
      float mx = fmaxf(fmaxf(fmaxf(a.x,a.y),fmaxf(a.z,a.w)), fmaxf(fmaxf(b4.x,b4.y),fmaxf(b4.z,b4.w)));
      float mn = fminf(fminf(fminf(a.x,a.y),fminf(a.z,a.w)), fminf(fminf(b4.x,b4.y),fminf(b4.z,b4.w)));
      dsum[cell_w*32+slot] = sm; dmax[cell_w*32+slot] = mx; dmin[cell_w*32+slot] = mn;
      __syncthreads();
      if (tid < 256) {
        int cell = tid >> 4, l = tid & 15;
        float s2 = dsum[cell*32+l] + dsum[cell*32+l+16];
        float m2 = fmaxf(dmax[cell*32+l], dmax[cell*32+l+16]);
        float n2 = fminf(dmin[cell*32+l], dmin[cell*32+l+16]);
        #pragma unroll
        for (int m = 8; m >= 1; m >>= 1) {
          s2 += __shfl_xor(s2, m, 16);
          m2 = fmaxf(m2, __shfl_xor(m2, m, 16));
          n2 = fminf(n2, __shfl_xor(n2, m, 16));
        }
        if (l == 0) { cm[cell] = s2*(1.f/256.f); cx[cell] = m2; cnn[cell] = n2; }
      }
      __syncthreads();
      #pragma unroll
      for (int j = 0; j < 2; ++j) {
        int idx = j*512 + tid;
        int cell = idx >> 6, e = idx & 63;
        float v = cm[cell]*Wd[e] + cx[cell]*Wd[64+e] + cnn[cell]*Wd[128+e] + bd[e];
        emb2[(((size_t)t*16 + cell)*256 + bid)*64 + e] = fmaxf(v, 0.f);
      }
      __syncthreads();
    }
  }

  // ---------- prologue B: weight transposes ----------
  { // Wt2[n][k][h][i]
    const int n2 = bid >> 4, ks = bid & 15;
    const int hh = tid & 127, k2 = tid >> 7;
    for (int kk = 0; kk < 16; kk += 4) {
      int k = ks*16 + kk + k2;
      float v[4];
      #pragma unroll
      for (int i = 0; i < 4; ++i) {
        int g = i*128 + hh;
        v[i] = (k < 128) ? W_ih[((size_t)n2*512 + g)*128 + k]
                         : W_hh[((size_t)n2*512 + g)*128 + (k-128)];
      }
      *(float4*)&Wt2[((size_t)n2*256 + k)*512 + hh*4] = make_float4(v[0],v[1],v[2],v[3]);
    }
  }
  { // WsT[n][e][h]
    const int n2 = bid & 15, e = (bid >> 4)*4 + (tid >> 7), hh = tid & 127;
    WsT[((size_t)n2*64 + e)*128 + hh] = Ws[((size_t)n2*128 + hh)*64 + e];
  }
  { // W_hoT[n][o][h]
    const int n2 = bid & 15, og = bid >> 4;
    for (int j = tid; j < 1024; j += 512) {
      int oo = og*8 + (j >> 7), hh = j & 127;
      W_hoT[((size_t)n2*128 + oo)*128 + hh] = W_ho[((size_t)n2*128 + hh)*128 + oo];
    }
  }
  if (bid < 16) { // bsum2[n][h][i]
    const int hh = tid & 127, i = tid >> 7;
    bsum2[((size_t)bid*128 + hh)*4 + i] = b_ih[bid*512 + i*128 + hh] + b_hh[bid*512 + i*128 + hh];
  }
  grid.sync();

  // ---------- main recurrence ----------
  const int n   = ((bid & 7) << 1) | ((bid >> 3) & 1);  // XCD-local node
  const int bt  = bid >> 4, b0c = bt*16;
  // GEMM map
  const int h   = tid >> 2, bq = tid & 3;
  const float4* Wk = (const float4*)Wt2 + (size_t)n*256*128 + h;
  const float4 bias4 = *((const float4*)bsum2 + (n*128 + h));
  // head map
  const int o = tid & 127, bq2 = tid >> 7;
  const float4* Wo4 = (const float4*)W_hoT + ((size_t)n*128 + o)*32;
  const float bho = b_ho[n*128 + o], wout = W_out[o];
  // social map
  const int es = tid & 63, bg = tid >> 6;
  const float4* Wss = (const float4*)WsT + ((size_t)n*64 + es)*32;
  // social staging map
  const int sb = tid >> 5, se2 = (tid & 31)*2;
  const float bs0 = bs[se2], bs1 = bs[se2+1];

  for (int t = 0; t < 48; ++t) {
    // ---- wait for previous step's social partials ----
    if (t > 0) {
      if (tid == 0) {
        while (__hip_atomic_load(&flag[(t-1)*16 + bt], __ATOMIC_ACQUIRE, __HIP_MEMORY_SCOPE_AGENT) < 16)
          __builtin_amdgcn_s_sleep(2);
      }
      __syncthreads();
    }
    // ---- stage sX: emb | social | h ----
    if (tid < 256) {
      int idx4 = tid*4; int b = idx4 >> 6, e = idx4 & 63;
      *(float4*)&sX[b*260 + e] = *(const float4*)&emb2[(((size_t)t*16 + n)*256 + b0c + b)*64 + e];
    }
    {
      float s0 = bs0, s1 = bs1;
      if (t > 0) {
        const float* pb = psoc + (size_t)((t&1)^1)*16*16384 + (size_t)(b0c + sb)*64 + se2;
        #pragma unroll
        for (int nn = 0; nn < 16; ++nn) {
          s0 += __hip_atomic_load(pb + (size_t)nn*16384,     __ATOMIC_RELAXED, __HIP_MEMORY_SCOPE_AGENT);
          s1 += __hip_atomic_load(pb + (size_t)nn*16384 + 1, __ATOMIC_RELAXED, __HIP_MEMORY_SCOPE_AGENT);
        }
      }
      sX[sb*260 + 64 + se2]     = fmaxf(s0, 0.f);
      sX[sb*260 + 64 + se2 + 1] = fmaxf(s1, 0.f);
    }
    { int idx4 = tid*4; int b = idx4 >> 7, h4 = idx4 & 127;
      *(float4*)&sX[b*260 + 128 + h4] = *(const float4*)&sH[b*132 + h4]; }
    __syncthreads();

    // ---- gates GEMM (K=256) + LSTM cell, in registers ----
    {
      float4 acc0={0,0,0,0}, acc1={0,0,0,0}, acc2={0,0,0,0}, acc3={0,0,0,0};
      const float* x0 = sX + (bq*4+0)*260; const float* x1 = sX + (bq*4+1)*260;
      const float* x2 = sX + (bq*4+2)*260; const float* x3 = sX + (bq*4+3)*260;
      #pragma unroll 2
      for (int c = 0; c < 64; ++c) {
        const int k = c*4;
        float4 w0 = Wk[(size_t)(k+0)*128], w1 = Wk[(size_t)(k+1)*128];
        float4 w2 = Wk[(size_t)(k+2)*128], w3 = Wk[(size_t)(k+3)*128];
        float4 xa = *(const float4*)(x0 + k), xb = *(const float4*)(x1 + k);
        float4 xc = *(const float4*)(x2 + k), xd = *(const float4*)(x3 + k);
        fma4(acc0, w0, xa.x); fma4(acc0, w1, xa.y); fma4(acc0, w2, xa.z); fma4(acc0, w3, xa.w);
        fma4(acc1, w0, xb.x); fma4(acc1, w1, xb.y); fma4(acc1, w2, xb.z); fma4(acc1, w3, xb.w);
        fma4(acc2, w0, xc.x); fma4(acc2, w1, xc.y); fma4(acc2, w2, xc.z); fma4(acc2, w3, xc.w);
        fma4(acc3, w0, xd.x); fma4(acc3, w1, xd.y); fma4(acc3, w2, xd.z); fma4(acc3, w3, xd.w);
      }
      float4 av[4] = {acc0, acc1, acc2, acc3};
      #pragma unroll
      for (int j = 0; j < 4; ++j) {
        const int b = bq*4 + j;
        float gi = av[j].x + bias4.x, gf = av[j].y + bias4.y;
        float gg = av[j].z + bias4.z, go = av[j].w + bias4.w;
        float cv = sC[b*132 + h];
        float cn = sigf(gf)*cv + sigf(gi)*tanhf(gg);
        float hn = sigf(go)*tanhf(cn);
        sC[b*132 + h] = cn; sH[b*132 + h] = hn;
      }
    }
    __syncthreads();

    // ---- social projection -> psoc (device-scope atomic stores) ----
    {
      float a0 = 0.f, a1 = 0.f;
      const float* hb0 = sH + (bg*2+0)*132;
      const float* hb1 = sH + (bg*2+1)*132;
      #pragma unroll 8
      for (int h4 = 0; h4 < 32; ++h4) {
        float4 w = Wss[h4];
        float4 xa = *(const float4*)(hb0 + h4*4);
        float4 xb = *(const float4*)(hb1 + h4*4);
        a0 = fmaf(w.x,xa.x, fmaf(w.y,xa.y, fmaf(w.z,xa.z, fmaf(w.w,xa.w, a0))));
        a1 = fmaf(w.x,xb.x, fmaf(w.y,xb.y, fmaf(w.z,xb.z, fmaf(w.w,xb.w, a1))));
      }
      const size_t pw = (size_t)(t&1)*16*16384 + (size_t)n*16384;
      __hip_atomic_store(&psoc[pw + (size_t)(b0c + bg*2+0)*64 + es], a0, __ATOMIC_RELAXED, __HIP_MEMORY_SCOPE_AGENT);
      __hip_atomic_store(&psoc[pw + (size_t)(b0c + bg*2+1)*64 + es], a1, __ATOMIC_RELAXED, __HIP_MEMORY_SCOPE_AGENT);
    }
    // ---- output head ----
    {
      float p0=0.f, p1=0.f, p2=0.f, p3=0.f;
      const float* hb0 = sH + (bq2*4+0)*132; const float* hb1 = sH + (bq2*4+1)*132;
      const float* hb2 = sH + (bq2*4+2)*132; const float* hb3 = sH + (bq2*4+3)*132;
      #pragma unroll 8
      for (int h4 = 0; h4 < 32; ++h4) {
        float4 w = Wo4[h4];
        float4 xa = *(const float4*)(hb0 + h4*4), xb = *(const float4*)(hb1 + h4*4);
        float4 xc = *(const float4*)(hb2 + h4*4), xd = *(const float4*)(hb3 + h4*4);
        p0 = fmaf(w.x,xa.x, fmaf(w.y,xa.y, fmaf(w.z,xa.z, fmaf(w.w,xa.w, p0))));
        p1 = fmaf(w.x,xb.x, fmaf(w.y,xb.y, fmaf(w.z,xb.z, fmaf(w.w,xb.w, p1))));
        p2 = fmaf(w.x,xc.x, fmaf(w.y,xc.y, fmaf(w.z,xc.z, fmaf(w.w,xc.w, p2))));
        p3 = fmaf(w.x,xd.x, fmaf(w.y,xd.y, fmaf(w.z,xd.z, fmaf(w.w,xd.w, p3))));
      }
      red[(bq2*4+0)*132 + o] = wout * sigf(p0 + bho);
      red[(bq2*4+1)*132 + o] = wout * sigf(p1 + bho);
      red[(bq2*4+2)*132 + o] = wout * sigf(p2 + bho);
      red[(bq2*4+3)*132 + o] = wout * sigf(p3 + bho);
    }
    __threadfence();
    __syncthreads();
    if (tid == 0)
      __hip_atomic_fetch_add(&flag[t*16 + bt], 1, __ATOMIC_RELEASE, __HIP_MEMORY_SCOPE_AGENT);
    // ---- y reduce ----
    if (tid < 256) {
      int bb = tid >> 4, l = tid & 15;
      float sm = 0.f;
      #pragma unroll
      for (int kk = 0; kk < 8; ++kk) sm += red[bb*132 + l + 16*kk];
      #pragma unroll
      for (int m = 8; m >= 1; m >>= 1) sm += __shfl_xor(sm, m, 16);
      if (l == 0) y[((size_t)t*256 + b0c + bb)*16 + n] = sm + b_out[0];
    }
  }
}

extern "C" void kernel_launch(void* const* d_in, const int* in_sizes, int n_in,
                              void* d_out, int out_size, void* d_ws, size_t ws_size,
                              hipStream_t stream){
  const float* x    = (const float*)d_in[0];
  const float* Wd   = (const float*)d_in[1];
  const float* bd   = (const float*)d_in[2];
  const float* Ws   = (const float*)d_in[3];
  const float* bs   = (const float*)d_in[4];
  const float* W_ih = (const float*)d_in[5];
  const float* b_ih = (const float*)d_in[6];
  const float* W_hh = (const float*)d_in[7];
  const float* b_hh = (const float*)d_in[8];
  const float* W_ho = (const float*)d_in[9];
  const float* b_ho = (const float*)d_in[10];
  const float* W_out= (const float*)d_in[11];
  const float* b_out= (const float*)d_in[12];
  float* y = (float*)d_out;

  float* ws = (float*)d_ws;
  float* emb2  = ws;                                  // 12,582,912
  float* Wt2   = emb2 + (size_t)12582912;             // 2,097,152
  float* WsT   = Wt2 + 2097152;                       // 131,072
  float* W_hoT = WsT + 131072;                        // 262,144
  float* bsum2 = W_hoT + 262144;                      // 8,192
  float* psoc  = bsum2 + 8192;                        // 524,288
  int*   flag  = (int*)(psoc + 524288);               // 768 ints

  void* args[] = { (void*)&x, (void*)&Wd, (void*)&bd, (void*)&Ws, (void*)&bs,
                   (void*)&W_ih, (void*)&b_ih, (void*)&W_hh, (void*)&b_hh,
                   (void*)&W_ho, (void*)&b_ho, (void*)&W_out, (void*)&b_out,
                   (void*)&y, (void*)&emb2, (void*)&Wt2, (void*)&WsT,
                   (void*)&W_hoT, (void*)&bsum2, (void*)&psoc, (void*)&flag };
  hipLaunchCooperativeKernel((const void*)k_fused, dim3(256), dim3(512), args, 0, stream);
}

// Round 4
// 2557.018 us; speedup vs baseline: 1.9785x; 1.4288x over previous
//
#include <hip/hip_runtime.h>
#include <hip/hip_cooperative_groups.h>
#include <cmath>

namespace cg = cooperative_groups;

// B=256, T=48, N2=16, E=64, H=128, G=4H=512
// Block = (node n, batch-tile bt of 16). Gate weights resident in VGPRs as bf16
// MFMA B-frags (wave w owns h-cols w*16..w*16+15 of ALL 4 gate types).
// c-state in registers, h in LDS. Gates GEMM = 32 MFMA/wave/step, zero memory.

typedef __attribute__((ext_vector_type(8))) short bf16x8;
typedef __attribute__((ext_vector_type(4))) float f32x4;

__device__ __forceinline__ float sigf(float x){ return 1.0f/(1.0f+expf(-x)); }
__device__ __forceinline__ unsigned short f2bf(float f){
  unsigned u = __builtin_bit_cast(unsigned, f);
  return (unsigned short)((u + 0x7FFFu + ((u>>16)&1u)) >> 16);
}
// XOR-swizzled byte address into sXb[16][512B]; k-byte 16B-group spread by row
__device__ __forceinline__ int ax(int b, int kb){ return (b<<9) + (kb ^ ((b&7)<<4)); }

__global__ __launch_bounds__(512, 2) void k_fused(
    const float* __restrict__ x, const float* __restrict__ Wd, const float* __restrict__ bd,
    const float* __restrict__ Ws, const float* __restrict__ bs,
    const float* __restrict__ W_ih, const float* __restrict__ b_ih,
    const float* __restrict__ W_hh, const float* __restrict__ b_hh,
    const float* __restrict__ W_ho, const float* __restrict__ b_ho,
    const float* __restrict__ W_out, const float* __restrict__ b_out,
    float* __restrict__ y,
    unsigned short* __restrict__ emb2b, float* __restrict__ WsT,
    float* __restrict__ W_hoT, float* __restrict__ psoc, int* __restrict__ flag)
{
  __shared__ unsigned char sXb[16*512];   // bf16 [b][k=256] swizzled: emb|social|h
  __shared__ float sH[16*132];            // fp32 h for social/head
  __shared__ float red[16*132];           // head partials / prologue scratch

  const int bid = blockIdx.x, tid = threadIdx.x;
  const int lane = tid & 63, w = tid >> 6;
  cg::grid_group grid = cg::this_grid();

  if (bid == 0) for (int j = tid; j < 16*48; j += 512) flag[j] = 0;

  // ---------- prologue A: downsample + embed for batch b = bid (bf16 out) ----------
  {
    float* dsum = red; float* dmax = red+512; float* dmin = red+1024;
    float* cm = red+1536; float* cx = red+1552; float* cnn = red+1568;
    const int r = tid >> 3, c0 = (tid & 7) * 8;
    const int cell_w = (r >> 4)*4 + (c0 >> 4);
    const int slot = (r & 15)*2 + ((c0 >> 3) & 1);
    for (int t = 0; t < 48; ++t) {
      const float* xp = x + ((size_t)bid*48 + t)*4096 + r*64 + c0;
      float4 a = *(const float4*)xp;
      float4 b4 = *(const float4*)(xp+4);
      float sm = a.x+a.y+a.z+a.w + b4.x+b4.y+b4.z+b4.w;
      float mx = fmaxf(fmaxf(fmaxf(a.x,a.y),fmaxf(a.z,a.w)), fmaxf(fmaxf(b4.x,b4.y),fmaxf(b4.z,b4.w)));
      float mn = fminf(fminf(fminf(a.x,a.y),fminf(a.z,a.w)), fminf(fminf(b4.x,b4.y),fminf(b4.z,b4.w)));
      dsum[cell_w*32+slot] = sm; dmax[cell_w*32+slot] = mx; dmin[cell_w*32+slot] = mn;
      __syncthreads();
      if (tid < 256) {
        int cell = tid >> 4, l = tid & 15;
        float s2 = dsum[cell*32+l] + dsum[cell*32+l+16];
        float m2 = fmaxf(dmax[cell*32+l], dmax[cell*32+l+16]);
        float n2 = fminf(dmin[cell*32+l], dmin[cell*32+l+16]);
        #pragma unroll
        for (int m = 8; m >= 1; m >>= 1) {
          s2 += __shfl_xor(s2, m, 16);
          m2 = fmaxf(m2, __shfl_xor(m2, m, 16));
          n2 = fminf(n2, __shfl_xor(n2, m, 16));
        }
        if (l == 0) { cm[cell] = s2*(1.f/256.f); cx[cell] = m2; cnn[cell] = n2; }
      }
      __syncthreads();
      #pragma unroll
      for (int j = 0; j < 2; ++j) {
        int idx = j*512 + tid;
        int cell = idx >> 6, e = idx & 63;
        float v = cm[cell]*Wd[e] + cx[cell]*Wd[64+e] + cnn[cell]*Wd[128+e] + bd[e];
        emb2b[(((size_t)t*16 + cell)*256 + bid)*64 + e] = f2bf(fmaxf(v, 0.f));
      }
      __syncthreads();
    }
  }

  // ---------- prologue B: WsT[n][e][h], W_hoT[n][o][h] ----------
  { const int n2 = bid & 15, e = (bid >> 4)*4 + (tid >> 7), hh = tid & 127;
    WsT[((size_t)n2*64 + e)*128 + hh] = Ws[((size_t)n2*128 + hh)*64 + e]; }
  { const int n2 = bid & 15, og = bid >> 4;
    for (int j = tid; j < 1024; j += 512) {
      int oo = og*8 + (j >> 7), hh = j & 127;
      W_hoT[((size_t)n2*128 + oo)*128 + hh] = W_ho[((size_t)n2*128 + hh)*128 + oo];
    } }

  // ---------- prologue C: resident bf16 B-frags + biases ----------
  const int n  = ((bid & 7) << 1) | ((bid >> 3) & 1);  // XCD-local node
  const int bt = bid >> 4, b0c = bt*16;
  const int hcol = w*16 + (lane & 15);
  bf16x8 bw[4][8];
  float bias[4];
  {
    const int krow = (lane >> 4)*8;
    #pragma unroll
    for (int G = 0; G < 4; ++G) {
      const float* srcI = W_ih + ((size_t)n*512 + G*128 + hcol)*128;
      const float* srcH = W_hh + ((size_t)n*512 + G*128 + hcol)*128;
      #pragma unroll
      for (int kt = 0; kt < 8; ++kt) {
        const float* s = (kt < 4) ? (srcI + kt*32 + krow) : (srcH + (kt-4)*32 + krow);
        float4 aa = *(const float4*)s;
        float4 bb = *(const float4*)(s+4);
        bf16x8 v;
        v[0]=(short)f2bf(aa.x); v[1]=(short)f2bf(aa.y); v[2]=(short)f2bf(aa.z); v[3]=(short)f2bf(aa.w);
        v[4]=(short)f2bf(bb.x); v[5]=(short)f2bf(bb.y); v[6]=(short)f2bf(bb.z); v[7]=(short)f2bf(bb.w);
        bw[G][kt] = v;
      }
      int gg = n*512 + G*128 + hcol;
      bias[G] = b_ih[gg] + b_hh[gg];
    }
  }
  // zero the h region of sX (h0 = 0)
  { int b = tid >> 5, j = tid & 31;
    *(uint2*)&sXb[ax(b, 256 + j*8)] = make_uint2(0u, 0u); }

  grid.sync();

  // ---------- per-thread maps for fp32 social/head ----------
  const int o = tid & 127, bq2 = tid >> 7;
  const float4* Wo4 = (const float4*)W_hoT + ((size_t)n*128 + o)*32;
  const float bho = b_ho[n*128 + o], wout = W_out[o];
  const int es = tid & 63, bg = tid >> 6;
  const float4* Wss = (const float4*)WsT + ((size_t)n*64 + es)*32;
  const int sb = tid >> 5, sj = tid & 31, se2 = sj*2;
  const float bs0 = bs[se2], bs1 = bs[se2+1];
  float creg[4] = {0.f, 0.f, 0.f, 0.f};

  for (int t = 0; t < 48; ++t) {
    // ---- wait for previous step's social partials ----
    if (t > 0) {
      if (tid == 0) {
        while (__hip_atomic_load(&flag[(t-1)*16 + bt], __ATOMIC_ACQUIRE, __HIP_MEMORY_SCOPE_AGENT) < 16)
          __builtin_amdgcn_s_sleep(2);
      }
      __syncthreads();
    }
    // ---- stage emb (bf16) ----
    { int b = tid >> 5;
      unsigned v = *(const unsigned*)&emb2b[(((size_t)t*16 + n)*256 + b0c + b)*64 + se2];
      *(unsigned*)&sXb[ax(b, sj*4)] = v; }
    // ---- social reduce -> relu -> bf16 stage ----
    { float s0 = bs0, s1 = bs1;
      if (t > 0) {
        const float* pb = psoc + (size_t)((t&1)^1)*16*16384 + (size_t)(b0c + sb)*64 + se2;
        #pragma unroll
        for (int nn = 0; nn < 16; ++nn) {
          s0 += __hip_atomic_load(pb + (size_t)nn*16384,     __ATOMIC_RELAXED, __HIP_MEMORY_SCOPE_AGENT);
          s1 += __hip_atomic_load(pb + (size_t)nn*16384 + 1, __ATOMIC_RELAXED, __HIP_MEMORY_SCOPE_AGENT);
        }
      }
      unsigned pk = (unsigned)f2bf(fmaxf(s0,0.f)) | ((unsigned)f2bf(fmaxf(s1,0.f)) << 16);
      *(unsigned*)&sXb[ax(sb, 128 + sj*4)] = pk; }
    __syncthreads();

    // ---- gates via MFMA (K=256), bias as C-in ----
    f32x4 acc[4];
    #pragma unroll
    for (int G = 0; G < 4; ++G) { f32x4 c0 = {bias[G], bias[G], bias[G], bias[G]}; acc[G] = c0; }
    {
      const int ab = lane & 15, akb = (lane >> 4)*16;
      #pragma unroll
      for (int kt = 0; kt < 8; ++kt) {
        bf16x8 aF = *(const bf16x8*)&sXb[ax(ab, kt*64 + akb)];
        #pragma unroll
        for (int G = 0; G < 4; ++G)
          acc[G] = __builtin_amdgcn_mfma_f32_16x16x32_bf16(aF, bw[G][kt], acc[G], 0, 0, 0);
      }
    }
    __syncthreads();   // all A-reads done before h overwrite

    // ---- LSTM cell in registers; D-frag row b=(lane>>4)*4+r, col h=hcol ----
    #pragma unroll
    for (int r = 0; r < 4; ++r) {
      int b = (lane >> 4)*4 + r;
      float cn = sigf(acc[1][r])*creg[r] + sigf(acc[0][r])*tanhf(acc[2][r]);
      float hn = sigf(acc[3][r])*tanhf(cn);
      creg[r] = cn;
      sH[b*132 + hcol] = hn;
      *(unsigned short*)&sXb[ax(b, 256 + hcol*2)] = f2bf(hn);
    }
    __syncthreads();

    // ---- social projection (fp32) -> psoc ----
    {
      float a0 = 0.f, a1 = 0.f;
      const float* hb0 = sH + (bg*2+0)*132;
      const float* hb1 = sH + (bg*2+1)*132;
      #pragma unroll 8
      for (int h4 = 0; h4 < 32; ++h4) {
        float4 ww = Wss[h4];
        float4 xa = *(const float4*)(hb0 + h4*4);
        float4 xb = *(const float4*)(hb1 + h4*4);
        a0 = fmaf(ww.x,xa.x, fmaf(ww.y,xa.y, fmaf(ww.z,xa.z, fmaf(ww.w,xa.w, a0))));
        a1 = fmaf(ww.x,xb.x, fmaf(ww.y,xb.y, fmaf(ww.z,xb.z, fmaf(ww.w,xb.w, a1))));
      }
      const size_t pw = (size_t)(t&1)*16*16384 + (size_t)n*16384;
      __hip_atomic_store(&psoc[pw + (size_t)(b0c + bg*2+0)*64 + es], a0, __ATOMIC_RELAXED, __HIP_MEMORY_SCOPE_AGENT);
      __hip_atomic_store(&psoc[pw + (size_t)(b0c + bg*2+1)*64 + es], a1, __ATOMIC_RELAXED, __HIP_MEMORY_SCOPE_AGENT);
    }
    __threadfence();
    __syncthreads();
    if (tid == 0)
      __hip_atomic_fetch_add(&flag[t*16 + bt], 1, __ATOMIC_RELEASE, __HIP_MEMORY_SCOPE_AGENT);

    // ---- output head (fp32) + y reduce ----
    {
      float p0=0.f, p1=0.f, p2=0.f, p3=0.f;
      const float* hb0 = sH + (bq2*4+0)*132; const float* hb1 = sH + (bq2*4+1)*132;
      const float* hb2 = sH + (bq2*4+2)*132; const float* hb3 = sH + (bq2*4+3)*132;
      #pragma unroll 8
      for (int h4 = 0; h4 < 32; ++h4) {
        float4 ww = Wo4[h4];
        float4 xa = *(const float4*)(hb0 + h4*4), xb = *(const float4*)(hb1 + h4*4);
        float4 xc = *(const float4*)(hb2 + h4*4), xd = *(const float4*)(hb3 + h4*4);
        p0 = fmaf(ww.x,xa.x, fmaf(ww.y,xa.y, fmaf(ww.z,xa.z, fmaf(ww.w,xa.w, p0))));
        p1 = fmaf(ww.x,xb.x, fmaf(ww.y,xb.y, fmaf(ww.z,xb.z, fmaf(ww.w,xb.w, p1))));
        p2 = fmaf(ww.x,xc.x, fmaf(ww.y,xc.y, fmaf(ww.z,xc.z, fmaf(ww.w,xc.w, p2))));
        p3 = fmaf(ww.x,xd.x, fmaf(ww.y,xd.y, fmaf(ww.z,xd.z, fmaf(ww.w,xd.w, p3))));
      }
      red[(bq2*4+0)*132 + o] = wout * sigf(p0 + bho);
      red[(bq2*4+1)*132 + o] = wout * sigf(p1 + bho);
      red[(bq2*4+2)*132 + o] = wout * sigf(p2 + bho);
      red[(bq2*4+3)*132 + o] = wout * sigf(p3 + bho);
    }
    __syncthreads();
    if (tid < 256) {
      int bb = tid >> 4, l = tid & 15;
      float sm = 0.f;
      #pragma unroll
      for (int kk = 0; kk < 8; ++kk) sm += red[bb*132 + l + 16*kk];
      #pragma unroll
      for (int m = 8; m >= 1; m >>= 1) sm += __shfl_xor(sm, m, 16);
      if (l == 0) y[((size_t)t*256 + b0c + bb)*16 + n] = sm + b_out[0];
    }
  }
}

extern "C" void kernel_launch(void* const* d_in, const int* in_sizes, int n_in,
                              void* d_out, int out_size, void* d_ws, size_t ws_size,
                              hipStream_t stream){
  const float* x    = (const float*)d_in[0];
  const float* Wd   = (const float*)d_in[1];
  const float* bd   = (const float*)d_in[2];
  const float* Ws   = (const float*)d_in[3];
  const float* bs   = (const float*)d_in[4];
  const float* W_ih = (const float*)d_in[5];
  const float* b_ih = (const float*)d_in[6];
  const float* W_hh = (const float*)d_in[7];
  const float* b_hh = (const float*)d_in[8];
  const float* W_ho = (const float*)d_in[9];
  const float* b_ho = (const float*)d_in[10];
  const float* W_out= (const float*)d_in[11];
  const float* b_out= (const float*)d_in[12];
  float* y = (float*)d_out;

  char* ws = (char*)d_ws;
  unsigned short* emb2b = (unsigned short*)ws;          // 12,582,912 ushort = 25 MB
  float* WsT   = (float*)(ws + 25165824);               // 131,072 f
  float* W_hoT = WsT + 131072;                          // 262,144 f
  float* psoc  = W_hoT + 262144;                        // 524,288 f
  int*   flag  = (int*)(psoc + 524288);                 // 768 int

  void* args[] = { (void*)&x, (void*)&Wd, (void*)&bd, (void*)&Ws, (void*)&bs,
                   (void*)&W_ih, (void*)&b_ih, (void*)&W_hh, (void*)&b_hh,
                   (void*)&W_ho, (void*)&b_ho, (void*)&W_out, (void*)&b_out,
                   (void*)&y, (void*)&emb2b, (void*)&WsT, (void*)&W_hoT,
                   (void*)&psoc, (void*)&flag };
  hipLaunchCooperativeKernel((const void*)k_fused, dim3(256), dim3(512), args, 0, stream);
}

// Round 5
// 1114.528 us; speedup vs baseline: 4.5393x; 2.2943x over previous
//
#include <hip/hip_runtime.h>
#include <hip/hip_cooperative_groups.h>
#include <cmath>

namespace cg = cooperative_groups;

// B=256, T=48, N2=16, E=64, H=128, G=4H=512
// Block = (node n, batch-tile bt of 16). Gate weights resident in VGPRs as bf16
// MFMA B-frags. c-state in registers, h in LDS. Cross-block exchange: psoc via
// sc1 (agent-scope relaxed) loads/stores + flag handshake with NO L2 fences —
// only per-thread vmcnt drains (stores are at device coherence point when retired).

typedef __attribute__((ext_vector_type(8))) short bf16x8;
typedef __attribute__((ext_vector_type(4))) float f32x4;

__device__ __forceinline__ float sigf(float x){ return 1.0f/(1.0f+expf(-x)); }
__device__ __forceinline__ unsigned short f2bf(float f){
  unsigned u = __builtin_bit_cast(unsigned, f);
  return (unsigned short)((u + 0x7FFFu + ((u>>16)&1u)) >> 16);
}
// XOR-swizzled byte address into sXb[16][512B]
__device__ __forceinline__ int ax(int b, int kb){ return (b<<9) + (kb ^ ((b&7)<<4)); }

__global__ __launch_bounds__(512, 2) void k_fused(
    const float* __restrict__ x, const float* __restrict__ Wd, const float* __restrict__ bd,
    const float* __restrict__ Ws, const float* __restrict__ bs,
    const float* __restrict__ W_ih, const float* __restrict__ b_ih,
    const float* __restrict__ W_hh, const float* __restrict__ b_hh,
    const float* __restrict__ W_ho, const float* __restrict__ b_ho,
    const float* __restrict__ W_out, const float* __restrict__ b_out,
    float* __restrict__ y,
    unsigned short* __restrict__ emb2b, float* __restrict__ WsT,
    float* __restrict__ W_hoT, float* __restrict__ psoc, int* __restrict__ flag)
{
  __shared__ unsigned char sXb[16*512];   // bf16 [b][k=256] swizzled: emb|social|h
  __shared__ float sH[16*132];            // fp32 h for social/head
  __shared__ float red[16*132];           // head partials / prologue scratch

  const int bid = blockIdx.x, tid = threadIdx.x;
  const int lane = tid & 63, w = tid >> 6;
  cg::grid_group grid = cg::this_grid();

  if (bid == 0) for (int j = tid; j < 16*48; j += 512) flag[j] = 0;

  // ---------- prologue A: downsample + embed for batch b = bid (bf16 out) ----------
  {
    float* dsum = red; float* dmax = red+512; float* dmin = red+1024;
    float* cm = red+1536; float* cx = red+1552; float* cnn = red+1568;
    const int r = tid >> 3, c0 = (tid & 7) * 8;
    const int cell_w = (r >> 4)*4 + (c0 >> 4);
    const int slot = (r & 15)*2 + ((c0 >> 3) & 1);
    for (int t = 0; t < 48; ++t) {
      const float* xp = x + ((size_t)bid*48 + t)*4096 + r*64 + c0;
      float4 a = *(const float4*)xp;
      float4 b4 = *(const float4*)(xp+4);
      float sm = a.x+a.y+a.z+a.w + b4.x+b4.y+b4.z+b4.w;
      float mx = fmaxf(fmaxf(fmaxf(a.x,a.y),fmaxf(a.z,a.w)), fmaxf(fmaxf(b4.x,b4.y),fmaxf(b4.z,b4.w)));
      float mn = fminf(fminf(fminf(a.x,a.y),fminf(a.z,a.w)), fminf(fminf(b4.x,b4.y),fminf(b4.z,b4.w)));
      dsum[cell_w*32+slot] = sm; dmax[cell_w*32+slot] = mx; dmin[cell_w*32+slot] = mn;
      __syncthreads();
      if (tid < 256) {
        int cell = tid >> 4, l = tid & 15;
        float s2 = dsum[cell*32+l] + dsum[cell*32+l+16];
        float m2 = fmaxf(dmax[cell*32+l], dmax[cell*32+l+16]);
        float n2 = fminf(dmin[cell*32+l], dmin[cell*32+l+16]);
        #pragma unroll
        for (int m = 8; m >= 1; m >>= 1) {
          s2 += __shfl_xor(s2, m, 16);
          m2 = fmaxf(m2, __shfl_xor(m2, m, 16));
          n2 = fminf(n2, __shfl_xor(n2, m, 16));
        }
        if (l == 0) { cm[cell] = s2*(1.f/256.f); cx[cell] = m2; cnn[cell] = n2; }
      }
      __syncthreads();
      #pragma unroll
      for (int j = 0; j < 2; ++j) {
        int idx = j*512 + tid;
        int cell = idx >> 6, e = idx & 63;
        float v = cm[cell]*Wd[e] + cx[cell]*Wd[64+e] + cnn[cell]*Wd[128+e] + bd[e];
        emb2b[(((size_t)t*16 + cell)*256 + bid)*64 + e] = f2bf(fmaxf(v, 0.f));
      }
      __syncthreads();
    }
  }

  // ---------- prologue B: WsT[n][e][h], W_hoT[n][o][h] ----------
  { const int n2 = bid & 15, e = (bid >> 4)*4 + (tid >> 7), hh = tid & 127;
    WsT[((size_t)n2*64 + e)*128 + hh] = Ws[((size_t)n2*128 + hh)*64 + e]; }
  { const int n2 = bid & 15, og = bid >> 4;
    for (int j = tid; j < 1024; j += 512) {
      int oo = og*8 + (j >> 7), hh = j & 127;
      W_hoT[((size_t)n2*128 + oo)*128 + hh] = W_ho[((size_t)n2*128 + hh)*128 + oo];
    } }

  // ---------- prologue C: resident bf16 B-frags + biases ----------
  const int n  = ((bid & 7) << 1) | ((bid >> 3) & 1);  // XCD-local node
  const int bt = bid >> 4, b0c = bt*16;
  const int hcol = w*16 + (lane & 15);
  bf16x8 bw[4][8];
  float bias[4];
  {
    const int krow = (lane >> 4)*8;
    #pragma unroll
    for (int G = 0; G < 4; ++G) {
      const float* srcI = W_ih + ((size_t)n*512 + G*128 + hcol)*128;
      const float* srcH = W_hh + ((size_t)n*512 + G*128 + hcol)*128;
      #pragma unroll
      for (int kt = 0; kt < 8; ++kt) {
        const float* s = (kt < 4) ? (srcI + kt*32 + krow) : (srcH + (kt-4)*32 + krow);
        float4 aa = *(const float4*)s;
        float4 bb = *(const float4*)(s+4);
        bf16x8 v;
        v[0]=(short)f2bf(aa.x); v[1]=(short)f2bf(aa.y); v[2]=(short)f2bf(aa.z); v[3]=(short)f2bf(aa.w);
        v[4]=(short)f2bf(bb.x); v[5]=(short)f2bf(bb.y); v[6]=(short)f2bf(bb.z); v[7]=(short)f2bf(bb.w);
        bw[G][kt] = v;
      }
      int gg = n*512 + G*128 + hcol;
      bias[G] = b_ih[gg] + b_hh[gg];
    }
  }
  // zero the h region of sX (h0 = 0)
  { int b = tid >> 5, j = tid & 31;
    *(uint2*)&sXb[ax(b, 256 + j*8)] = make_uint2(0u, 0u); }

  grid.sync();

  // ---------- per-thread maps for fp32 social/head ----------
  const int o = tid & 127, bq2 = tid >> 7;
  const float4* Wo4 = (const float4*)W_hoT + ((size_t)n*128 + o)*32;
  const float bho = b_ho[n*128 + o], wout = W_out[o];
  const int es = tid & 63, bg = tid >> 6;
  const float4* Wss = (const float4*)WsT + ((size_t)n*64 + es)*32;
  const int sb = tid >> 5, sj = tid & 31, se2 = sj*2;
  const float bs0 = bs[se2], bs1 = bs[se2+1];
  float creg[4] = {0.f, 0.f, 0.f, 0.f};

  for (int t = 0; t < 48; ++t) {
    // ---- wait for previous step's social partials (relaxed poll, no inv) ----
    if (t > 0) {
      if (tid == 0) {
        while (__hip_atomic_load(&flag[(t-1)*16 + bt], __ATOMIC_RELAXED, __HIP_MEMORY_SCOPE_AGENT) < 16)
          __builtin_amdgcn_s_sleep(1);
      }
      __syncthreads();
    }
    // ---- stage emb (bf16) ----
    { int b = tid >> 5;
      unsigned v = *(const unsigned*)&emb2b[(((size_t)t*16 + n)*256 + b0c + b)*64 + se2];
      *(unsigned*)&sXb[ax(b, sj*4)] = v; }
    // ---- social reduce -> relu -> bf16 stage ----
    { float s0 = bs0, s1 = bs1;
      if (t > 0) {
        const float* pb = psoc + (size_t)((t&1)^1)*16*16384 + (size_t)(b0c + sb)*64 + se2;
        #pragma unroll
        for (int nn = 0; nn < 16; ++nn) {
          s0 += __hip_atomic_load(pb + (size_t)nn*16384,     __ATOMIC_RELAXED, __HIP_MEMORY_SCOPE_AGENT);
          s1 += __hip_atomic_load(pb + (size_t)nn*16384 + 1, __ATOMIC_RELAXED, __HIP_MEMORY_SCOPE_AGENT);
        }
      }
      unsigned pk = (unsigned)f2bf(fmaxf(s0,0.f)) | ((unsigned)f2bf(fmaxf(s1,0.f)) << 16);
      *(unsigned*)&sXb[ax(sb, 128 + sj*4)] = pk; }
    __syncthreads();

    // ---- gates via MFMA (K=256), bias as C-in ----
    f32x4 acc[4];
    #pragma unroll
    for (int G = 0; G < 4; ++G) { f32x4 c0 = {bias[G], bias[G], bias[G], bias[G]}; acc[G] = c0; }
    {
      const int ab = lane & 15, akb = (lane >> 4)*16;
      #pragma unroll
      for (int kt = 0; kt < 8; ++kt) {
        bf16x8 aF = *(const bf16x8*)&sXb[ax(ab, kt*64 + akb)];
        #pragma unroll
        for (int G = 0; G < 4; ++G)
          acc[G] = __builtin_amdgcn_mfma_f32_16x16x32_bf16(aF, bw[G][kt], acc[G], 0, 0, 0);
      }
    }
    __syncthreads();   // all A-reads done before h overwrite

    // ---- LSTM cell in registers; D-frag row b=(lane>>4)*4+r, col h=hcol ----
    #pragma unroll
    for (int r = 0; r < 4; ++r) {
      int b = (lane >> 4)*4 + r;
      float cn = sigf(acc[1][r])*creg[r] + sigf(acc[0][r])*tanhf(acc[2][r]);
      float hn = sigf(acc[3][r])*tanhf(cn);
      creg[r] = cn;
      sH[b*132 + hcol] = hn;
      *(unsigned short*)&sXb[ax(b, 256 + hcol*2)] = f2bf(hn);
    }
    __syncthreads();

    // ---- social projection (fp32) -> psoc (sc1 stores, device-coherent) ----
    {
      float a0 = 0.f, a1 = 0.f;
      const float* hb0 = sH + (bg*2+0)*132;
      const float* hb1 = sH + (bg*2+1)*132;
      #pragma unroll 8
      for (int h4 = 0; h4 < 32; ++h4) {
        float4 ww = Wss[h4];
        float4 xa = *(const float4*)(hb0 + h4*4);
        float4 xb = *(const float4*)(hb1 + h4*4);
        a0 = fmaf(ww.x,xa.x, fmaf(ww.y,xa.y, fmaf(ww.z,xa.z, fmaf(ww.w,xa.w, a0))));
        a1 = fmaf(ww.x,xb.x, fmaf(ww.y,xb.y, fmaf(ww.z,xb.z, fmaf(ww.w,xb.w, a1))));
      }
      const size_t pw = (size_t)(t&1)*16*16384 + (size_t)n*16384;
      __hip_atomic_store(&psoc[pw + (size_t)(b0c + bg*2+0)*64 + es], a0, __ATOMIC_RELAXED, __HIP_MEMORY_SCOPE_AGENT);
      __hip_atomic_store(&psoc[pw + (size_t)(b0c + bg*2+1)*64 + es], a1, __ATOMIC_RELAXED, __HIP_MEMORY_SCOPE_AGENT);
    }
    // drain own sc1 stores to coherence point (no L2 writeback needed)
    asm volatile("s_waitcnt vmcnt(0)" ::: "memory");
    __syncthreads();
    if (tid == 0)
      __hip_atomic_fetch_add(&flag[t*16 + bt], 1, __ATOMIC_RELAXED, __HIP_MEMORY_SCOPE_AGENT);

    // ---- output head (fp32) + y reduce ----
    {
      float p0=0.f, p1=0.f, p2=0.f, p3=0.f;
      const float* hb0 = sH + (bq2*4+0)*132; const float* hb1 = sH + (bq2*4+1)*132;
      const float* hb2 = sH + (bq2*4+2)*132; const float* hb3 = sH + (bq2*4+3)*132;
      #pragma unroll 8
      for (int h4 = 0; h4 < 32; ++h4) {
        float4 ww = Wo4[h4];
        float4 xa = *(const float4*)(hb0 + h4*4), xb = *(const float4*)(hb1 + h4*4);
        float4 xc = *(const float4*)(hb2 + h4*4), xd = *(const float4*)(hb3 + h4*4);
        p0 = fmaf(ww.x,xa.x, fmaf(ww.y,xa.y, fmaf(ww.z,xa.z, fmaf(ww.w,xa.w, p0))));
        p1 = fmaf(ww.x,xb.x, fmaf(ww.y,xb.y, fmaf(ww.z,xb.z, fmaf(ww.w,xb.w, p1))));
        p2 = fmaf(ww.x,xc.x, fmaf(ww.y,xc.y, fmaf(ww.z,xc.z, fmaf(ww.w,xc.w, p2))));
        p3 = fmaf(ww.x,xd.x, fmaf(ww.y,xd.y, fmaf(ww.z,xd.z, fmaf(ww.w,xd.w, p3))));
      }
      red[(bq2*4+0)*132 + o] = wout * sigf(p0 + bho);
      red[(bq2*4+1)*132 + o] = wout * sigf(p1 + bho);
      red[(bq2*4+2)*132 + o] = wout * sigf(p2 + bho);
      red[(bq2*4+3)*132 + o] = wout * sigf(p3 + bho);
    }
    __syncthreads();
    if (tid < 256) {
      int bb = tid >> 4, l = tid & 15;
      float sm = 0.f;
      #pragma unroll
      for (int kk = 0; kk < 8; ++kk) sm += red[bb*132 + l + 16*kk];
      #pragma unroll
      for (int m = 8; m >= 1; m >>= 1) sm += __shfl_xor(sm, m, 16);
      if (l == 0) y[((size_t)t*256 + b0c + bb)*16 + n] = sm + b_out[0];
    }
  }
}

extern "C" void kernel_launch(void* const* d_in, const int* in_sizes, int n_in,
                              void* d_out, int out_size, void* d_ws, size_t ws_size,
                              hipStream_t stream){
  const float* x    = (const float*)d_in[0];
  const float* Wd   = (const float*)d_in[1];
  const float* bd   = (const float*)d_in[2];
  const float* Ws   = (const float*)d_in[3];
  const float* bs   = (const float*)d_in[4];
  const float* W_ih = (const float*)d_in[5];
  const float* b_ih = (const float*)d_in[6];
  const float* W_hh = (const float*)d_in[7];
  const float* b_hh = (const float*)d_in[8];
  const float* W_ho = (const float*)d_in[9];
  const float* b_ho = (const float*)d_in[10];
  const float* W_out= (const float*)d_in[11];
  const float* b_out= (const float*)d_in[12];
  float* y = (float*)d_out;

  char* ws = (char*)d_ws;
  unsigned short* emb2b = (unsigned short*)ws;          // 12,582,912 ushort = 25 MB
  float* WsT   = (float*)(ws + 25165824);               // 131,072 f
  float* W_hoT = WsT + 131072;                          // 262,144 f
  float* psoc  = W_hoT + 262144;                        // 524,288 f
  int*   flag  = (int*)(psoc + 524288);                 // 768 int

  void* args[] = { (void*)&x, (void*)&Wd, (void*)&bd, (void*)&Ws, (void*)&bs,
                   (void*)&W_ih, (void*)&b_ih, (void*)&W_hh, (void*)&b_hh,
                   (void*)&W_ho, (void*)&b_ho, (void*)&W_out, (void*)&b_out,
                   (void*)&y, (void*)&emb2b, (void*)&WsT, (void*)&W_hoT,
                   (void*)&psoc, (void*)&flag };
  hipLaunchCooperativeKernel((const void*)k_fused, dim3(256), dim3(512), args, 0, stream);
}

// Round 6
// 893.476 us; speedup vs baseline: 5.6624x; 1.2474x over previous
//
#include <hip/hip_runtime.h>
#include <hip/hip_cooperative_groups.h>
#include <cmath>

namespace cg = cooperative_groups;

// B=256, T=48, N2=16, E=64, H=128, G=4H=512
// Block = (node n, batch-tile bt of 16). Gate weights resident in VGPRs/AGPRs as
// bf16 MFMA B-frags; social (Ws) and head (W_ho) weights pre-packed as bf16
// B-frags in LDS. c-state in registers; h staged bf16 in sXb (swizzled) and
// consumed by gates/social/head MFMAs. Cross-block: psoc via agent-scope relaxed
// (sc1) loads/stores + flag handshake, no L2 fences (vmcnt drain only).

typedef __attribute__((ext_vector_type(8))) short bf16x8;
typedef __attribute__((ext_vector_type(4))) float f32x4;

__device__ __forceinline__ float fexp2(float x){ return __builtin_amdgcn_exp2f(x); }
__device__ __forceinline__ float frcp(float x){ return __builtin_amdgcn_rcpf(x); }
__device__ __forceinline__ float sigf(float x){ return frcp(1.0f + fexp2(-1.44269504f*x)); }
__device__ __forceinline__ float tanh_f(float x){ return 1.0f - 2.0f*frcp(1.0f + fexp2(2.88539008f*x)); }
__device__ __forceinline__ unsigned short f2bf(float f){
  unsigned u = __builtin_bit_cast(unsigned, f);
  return (unsigned short)((u + 0x7FFFu + ((u>>16)&1u)) >> 16);
}
// XOR-swizzled byte address into sXb[16][512B]
__device__ __forceinline__ int ax(int b, int kb){ return (b<<9) + (kb ^ ((b&7)<<4)); }

// dynamic LDS partition (bytes)
#define OFF_WOF 0        // 32768: head B-frags  8w*4kt*64lane*16B
#define OFF_WSF 32768    // 16384: social B-frags 4w*4kt*64lane*16B
#define OFF_XB  49152    // 8192:  sXb bf16 [b][k=256] swizzled (emb|social|h)
#define OFF_RED 57344    // 8448:  red[16][132] fp32 (also prologue scratch)
#define SMEM_BYTES 65792

__global__ __launch_bounds__(512, 2) void k_fused(
    const float* __restrict__ x, const float* __restrict__ Wd, const float* __restrict__ bd,
    const float* __restrict__ Ws, const float* __restrict__ bs,
    const float* __restrict__ W_ih, const float* __restrict__ b_ih,
    const float* __restrict__ W_hh, const float* __restrict__ b_hh,
    const float* __restrict__ W_ho, const float* __restrict__ b_ho,
    const float* __restrict__ W_out, const float* __restrict__ b_out,
    float* __restrict__ y,
    unsigned short* __restrict__ emb2b, float* __restrict__ psoc, int* __restrict__ flag)
{
  extern __shared__ unsigned char smem[];
  unsigned char* sWoF = smem + OFF_WOF;
  unsigned char* sWsF = smem + OFF_WSF;
  unsigned char* sXb  = smem + OFF_XB;
  float* red          = (float*)(smem + OFF_RED);

  const int bid = blockIdx.x, tid = threadIdx.x;
  const int lane = tid & 63, w = tid >> 6;
  cg::grid_group grid = cg::this_grid();

  if (bid == 0) for (int j = tid; j < 16*48; j += 512) flag[j] = 0;

  // ---------- prologue A: downsample + embed for batch b = bid (bf16 out) ----------
  {
    float* dsum = red; float* dmax = red+512; float* dmin = red+1024;
    float* cm = red+1536; float* cx = red+1552; float* cnn = red+1568;
    const int r = tid >> 3, c0 = (tid & 7) * 8;
    const int cell_w = (r >> 4)*4 + (c0 >> 4);
    const int slot = (r & 15)*2 + ((c0 >> 3) & 1);
    for (int t = 0; t < 48; ++t) {
      const float* xp = x + ((size_t)bid*48 + t)*4096 + r*64 + c0;
      float4 a = *(const float4*)xp;
      float4 b4 = *(const float4*)(xp+4);
      float sm = a.x+a.y+a.z+a.w + b4.x+b4.y+b4.z+b4.w;
      float mx = fmaxf(fmaxf(fmaxf(a.x,a.y),fmaxf(a.z,a.w)), fmaxf(fmaxf(b4.x,b4.y),fmaxf(b4.z,b4.w)));
      float mn = fminf(fminf(fminf(a.x,a.y),fminf(a.z,a.w)), fminf(fminf(b4.x,b4.y),fminf(b4.z,b4.w)));
      dsum[cell_w*32+slot] = sm; dmax[cell_w*32+slot] = mx; dmin[cell_w*32+slot] = mn;
      __syncthreads();
      if (tid < 256) {
        int cell = tid >> 4, l = tid & 15;
        float s2 = dsum[cell*32+l] + dsum[cell*32+l+16];
        float m2 = fmaxf(dmax[cell*32+l], dmax[cell*32+l+16]);
        float n2 = fminf(dmin[cell*32+l], dmin[cell*32+l+16]);
        #pragma unroll
        for (int m = 8; m >= 1; m >>= 1) {
          s2 += __shfl_xor(s2, m, 16);
          m2 = fmaxf(m2, __shfl_xor(m2, m, 16));
          n2 = fminf(n2, __shfl_xor(n2, m, 16));
        }
        if (l == 0) { cm[cell] = s2*(1.f/256.f); cx[cell] = m2; cnn[cell] = n2; }
      }
      __syncthreads();
      #pragma unroll
      for (int j = 0; j < 2; ++j) {
        int idx = j*512 + tid;
        int cell = idx >> 6, e = idx & 63;
        float v = cm[cell]*Wd[e] + cx[cell]*Wd[64+e] + cnn[cell]*Wd[128+e] + bd[e];
        emb2b[(((size_t)t*16 + cell)*256 + bid)*64 + e] = f2bf(fmaxf(v, 0.f));
      }
      __syncthreads();
    }
  }

  const int n  = ((bid & 7) << 1) | ((bid >> 3) & 1);  // XCD-local node
  const int bt = bid >> 4, b0c = bt*16;

  // ---------- prologue B: pack Ws / W_ho into LDS as bf16 B-frags ----------
  __syncthreads();
  for (int s = tid; s < 1024; s += 512) {               // social: wv<4
    int wv = s >> 8, kt = (s >> 6) & 3, ln = s & 63;
    int e = wv*16 + (ln & 15), kb = kt*32 + (ln >> 4)*8;
    const float* src = Ws + (size_t)n*8192 + (size_t)kb*64 + e;
    bf16x8 v;
    #pragma unroll
    for (int j = 0; j < 8; ++j) v[j] = (short)f2bf(src[(size_t)j*64]);
    *(bf16x8*)&sWsF[s*16] = v;
  }
  for (int s = tid; s < 2048; s += 512) {               // head: wv<8
    int wv = s >> 8, kt = (s >> 6) & 3, ln = s & 63;
    int o = wv*16 + (ln & 15), kb = kt*32 + (ln >> 4)*8;
    const float* src = W_ho + (size_t)n*16384 + (size_t)kb*128 + o;
    bf16x8 v;
    #pragma unroll
    for (int j = 0; j < 8; ++j) v[j] = (short)f2bf(src[(size_t)j*128]);
    *(bf16x8*)&sWoF[s*16] = v;
  }

  // ---------- prologue C: resident bf16 gate B-frags + biases ----------
  const int hcol = w*16 + (lane & 15);
  bf16x8 bw[4][8];
  float bias[4];
  {
    const int krow = (lane >> 4)*8;
    #pragma unroll
    for (int G = 0; G < 4; ++G) {
      const float* srcI = W_ih + ((size_t)n*512 + G*128 + hcol)*128;
      const float* srcH = W_hh + ((size_t)n*512 + G*128 + hcol)*128;
      #pragma unroll
      for (int kt = 0; kt < 8; ++kt) {
        const float* s = (kt < 4) ? (srcI + kt*32 + krow) : (srcH + (kt-4)*32 + krow);
        float4 aa = *(const float4*)s;
        float4 bb = *(const float4*)(s+4);
        bf16x8 v;
        v[0]=(short)f2bf(aa.x); v[1]=(short)f2bf(aa.y); v[2]=(short)f2bf(aa.z); v[3]=(short)f2bf(aa.w);
        v[4]=(short)f2bf(bb.x); v[5]=(short)f2bf(bb.y); v[6]=(short)f2bf(bb.z); v[7]=(short)f2bf(bb.w);
        bw[G][kt] = v;
      }
      int gg = n*512 + G*128 + hcol;
      bias[G] = b_ih[gg] + b_hh[gg];
    }
  }
  // zero the h region of sXb (h0 = 0)
  { int b = tid >> 5, j = tid & 31;
    *(uint2*)&sXb[ax(b, 256 + j*8)] = make_uint2(0u, 0u); }

  grid.sync();

  // ---------- per-thread maps ----------
  const int ocol = w*16 + (lane & 15);
  const float bho = b_ho[n*128 + ocol], wout = W_out[ocol];
  const int sb = tid >> 5, sj = tid & 31, se2 = sj*2;
  const float bs0 = bs[se2], bs1 = bs[se2+1];
  float creg[4] = {0.f, 0.f, 0.f, 0.f};

  for (int t = 0; t < 48; ++t) {
    // ---- stage emb (independent of handshake) ----
    { unsigned v = *(const unsigned*)&emb2b[(((size_t)t*16 + n)*256 + b0c + sb)*64 + se2];
      *(unsigned*)&sXb[ax(sb, sj*4)] = v; }
    // ---- wait for previous step's social partials (all-thread wave-coalesced poll) ----
    if (t > 0) {
      while (__hip_atomic_load(&flag[(t-1)*16 + bt], __ATOMIC_RELAXED, __HIP_MEMORY_SCOPE_AGENT) < 16)
        __builtin_amdgcn_s_sleep(1);
    }
    // ---- social reduce -> relu -> bf16 stage ----
    { float s0 = bs0, s1 = bs1;
      if (t > 0) {
        const float* pb = psoc + (size_t)((t&1)^1)*16*16384 + (size_t)(b0c + sb)*64 + se2;
        #pragma unroll
        for (int nn = 0; nn < 16; ++nn) {
          s0 += __hip_atomic_load(pb + (size_t)nn*16384,     __ATOMIC_RELAXED, __HIP_MEMORY_SCOPE_AGENT);
          s1 += __hip_atomic_load(pb + (size_t)nn*16384 + 1, __ATOMIC_RELAXED, __HIP_MEMORY_SCOPE_AGENT);
        }
      }
      unsigned pk = (unsigned)f2bf(fmaxf(s0,0.f)) | ((unsigned)f2bf(fmaxf(s1,0.f)) << 16);
      *(unsigned*)&sXb[ax(sb, 128 + sj*4)] = pk; }
    __syncthreads();

    // ---- gates via MFMA (K=256), bias as C-in ----
    f32x4 acc[4];
    #pragma unroll
    for (int G = 0; G < 4; ++G) { f32x4 c0 = {bias[G], bias[G], bias[G], bias[G]}; acc[G] = c0; }
    {
      const int ab = lane & 15, akb = (lane >> 4)*16;
      #pragma unroll
      for (int kt = 0; kt < 8; ++kt) {
        bf16x8 aF = *(const bf16x8*)&sXb[ax(ab, kt*64 + akb)];
        #pragma unroll
        for (int G = 0; G < 4; ++G)
          acc[G] = __builtin_amdgcn_mfma_f32_16x16x32_bf16(aF, bw[G][kt], acc[G], 0, 0, 0);
      }
    }
    __syncthreads();   // all A-reads done before h overwrite

    // ---- LSTM cell in registers; write h (bf16) ----
    #pragma unroll
    for (int r = 0; r < 4; ++r) {
      int b = (lane >> 4)*4 + r;
      float cn = sigf(acc[1][r])*creg[r] + sigf(acc[0][r])*tanh_f(acc[2][r]);
      float hn = sigf(acc[3][r])*tanh_f(cn);
      creg[r] = cn;
      *(unsigned short*)&sXb[ax(b, 256 + hcol*2)] = f2bf(hn);
    }
    __syncthreads();   // h ready

    // ---- social (waves 0-3) + head (all waves) via MFMA on bf16 h ----
    f32x4 ph = {bho, bho, bho, bho};
    f32x4 ps = {0.f, 0.f, 0.f, 0.f};
    {
      const int ab = lane & 15, akb = (lane >> 4)*16;
      #pragma unroll
      for (int kt = 0; kt < 4; ++kt) {
        bf16x8 aH = *(const bf16x8*)&sXb[ax(ab, 256 + kt*64 + akb)];
        bf16x8 bo = *(const bf16x8*)&sWoF[((w*4 + kt)*64 + lane)*16];
        ph = __builtin_amdgcn_mfma_f32_16x16x32_bf16(aH, bo, ph, 0, 0, 0);
        if (w < 4) {
          bf16x8 bs_ = *(const bf16x8*)&sWsF[((w*4 + kt)*64 + lane)*16];
          ps = __builtin_amdgcn_mfma_f32_16x16x32_bf16(aH, bs_, ps, 0, 0, 0);
        }
      }
    }
    if (w < 4) {
      const size_t pw = (size_t)(t&1)*16*16384 + (size_t)n*16384;
      const int ecol = w*16 + (lane & 15);
      #pragma unroll
      for (int r = 0; r < 4; ++r) {
        int b = b0c + (lane >> 4)*4 + r;
        __hip_atomic_store(&psoc[pw + (size_t)b*64 + ecol], ps[r], __ATOMIC_RELAXED, __HIP_MEMORY_SCOPE_AGENT);
      }
    }
    asm volatile("s_waitcnt vmcnt(0)" ::: "memory");   // psoc stores at coherence point
    __syncthreads();
    if (tid == 0)
      __hip_atomic_fetch_add(&flag[t*16 + bt], 1, __ATOMIC_RELAXED, __HIP_MEMORY_SCOPE_AGENT);

    // ---- head epilogue + y reduce ----
    #pragma unroll
    for (int r = 0; r < 4; ++r) {
      int b = (lane >> 4)*4 + r;
      red[b*132 + ocol] = wout * sigf(ph[r]);
    }
    __syncthreads();
    if (tid < 256) {
      int bb = tid >> 4, l = tid & 15;
      float sm = 0.f;
      #pragma unroll
      for (int kk = 0; kk < 8; ++kk) sm += red[bb*132 + l + 16*kk];
      #pragma unroll
      for (int m = 8; m >= 1; m >>= 1) sm += __shfl_xor(sm, m, 16);
      if (l == 0) y[((size_t)t*256 + b0c + bb)*16 + n] = sm + b_out[0];
    }
  }
}

extern "C" void kernel_launch(void* const* d_in, const int* in_sizes, int n_in,
                              void* d_out, int out_size, void* d_ws, size_t ws_size,
                              hipStream_t stream){
  const float* x    = (const float*)d_in[0];
  const float* Wd   = (const float*)d_in[1];
  const float* bd   = (const float*)d_in[2];
  const float* Ws   = (const float*)d_in[3];
  const float* bs   = (const float*)d_in[4];
  const float* W_ih = (const float*)d_in[5];
  const float* b_ih = (const float*)d_in[6];
  const float* W_hh = (const float*)d_in[7];
  const float* b_hh = (const float*)d_in[8];
  const float* W_ho = (const float*)d_in[9];
  const float* b_ho = (const float*)d_in[10];
  const float* W_out= (const float*)d_in[11];
  const float* b_out= (const float*)d_in[12];
  float* y = (float*)d_out;

  char* ws = (char*)d_ws;
  unsigned short* emb2b = (unsigned short*)ws;          // 12,582,912 ushort = 25 MB
  float* psoc  = (float*)(ws + 25165824);               // 524,288 f (double-buffered)
  int*   flag  = (int*)(psoc + 524288);                 // 768 int

  hipFuncSetAttribute((const void*)k_fused, hipFuncAttributeMaxDynamicSharedMemorySize, SMEM_BYTES);

  void* args[] = { (void*)&x, (void*)&Wd, (void*)&bd, (void*)&Ws, (void*)&bs,
                   (void*)&W_ih, (void*)&b_ih, (void*)&W_hh, (void*)&b_hh,
                   (void*)&W_ho, (void*)&b_ho, (void*)&W_out, (void*)&b_out,
                   (void*)&y, (void*)&emb2b, (void*)&psoc, (void*)&flag };
  hipLaunchCooperativeKernel((const void*)k_fused, dim3(256), dim3(512), args, SMEM_BYTES, stream);
}

// Round 7
// 352.755 us; speedup vs baseline: 14.3419x; 2.5329x over previous
//
#include <hip/hip_runtime.h>
#include <hip/hip_cooperative_groups.h>
#include <cmath>

namespace cg = cooperative_groups;

// B=256, T=48, N2=16, E=64, H=128, G=4H=512
// Block = (node n, batch-tile bt of 16). Gate weights resident in VGPRs as bf16
// MFMA B-frags; Ws / W_ho pre-packed bf16 B-frags in LDS. c-state in registers;
// h staged bf16 in swizzled sXb. Cross-block: psoc via sc1 relaxed loads/stores;
// handshake = per-producer padded flag slots (plain sc1 store + 16-lane poll),
// no RMW, no L2 fences (per-wave vmcnt drain only).

typedef __attribute__((ext_vector_type(8))) short bf16x8;
typedef __attribute__((ext_vector_type(4))) float f32x4;

__device__ __forceinline__ float fexp2(float x){ return __builtin_amdgcn_exp2f(x); }
__device__ __forceinline__ float frcp(float x){ return __builtin_amdgcn_rcpf(x); }
__device__ __forceinline__ float sigf(float x){ return frcp(1.0f + fexp2(-1.44269504f*x)); }
__device__ __forceinline__ float tanh_f(float x){ return 1.0f - 2.0f*frcp(1.0f + fexp2(2.88539008f*x)); }
__device__ __forceinline__ unsigned short f2bf(float f){
  unsigned u = __builtin_bit_cast(unsigned, f);
  return (unsigned short)((u + 0x7FFFu + ((u>>16)&1u)) >> 16);
}
// XOR-swizzled byte address into sXb[16][512B]
__device__ __forceinline__ int ax(int b, int kb){ return (b<<9) + (kb ^ ((b&7)<<4)); }

// dynamic LDS partition (bytes)
#define OFF_WOF 0        // 32768: head B-frags  8w*4kt*64lane*16B
#define OFF_WSF 32768    // 16384: social B-frags 4w*4kt*64lane*16B
#define OFF_XB  49152    // 8192:  sXb bf16 [b][k=256] swizzled (emb|social|h)
#define OFF_RED 57344    // 8448:  red[16][132] fp32 (also prologue scratch)
#define SMEM_BYTES 65792

__global__ __launch_bounds__(512, 2) void k_fused(
    const float* __restrict__ x, const float* __restrict__ Wd, const float* __restrict__ bd,
    const float* __restrict__ Ws, const float* __restrict__ bs,
    const float* __restrict__ W_ih, const float* __restrict__ b_ih,
    const float* __restrict__ W_hh, const float* __restrict__ b_hh,
    const float* __restrict__ W_ho, const float* __restrict__ b_ho,
    const float* __restrict__ W_out, const float* __restrict__ b_out,
    float* __restrict__ y,
    unsigned short* __restrict__ emb2b, float* __restrict__ psoc, int* __restrict__ flagv)
{
  extern __shared__ unsigned char smem[];
  unsigned char* sWoF = smem + OFF_WOF;
  unsigned char* sWsF = smem + OFF_WSF;
  unsigned char* sXb  = smem + OFF_XB;
  float* red          = (float*)(smem + OFF_RED);

  const int bid = blockIdx.x, tid = threadIdx.x;
  const int lane = tid & 63, w = tid >> 6;
  cg::grid_group grid = cg::this_grid();

  const int n  = ((bid & 7) << 1) | ((bid >> 3) & 1);  // XCD-local node
  const int bt = bid >> 4, b0c = bt*16;

  // zero own flag slots (sc1, drained before grid.sync)
  if (tid == 0) {
    for (int tt = 0; tt < 48; ++tt)
      __hip_atomic_store(&flagv[((tt*16 + bt)*16 + n)*16], 0, __ATOMIC_RELAXED, __HIP_MEMORY_SCOPE_AGENT);
  }

  // ---------- prologue A: downsample + embed for batch b = bid (bf16 out) ----------
  {
    float* dsum = red; float* dmax = red+512; float* dmin = red+1024;
    float* cm = red+1536; float* cx = red+1552; float* cnn = red+1568;
    const int r = tid >> 3, c0 = (tid & 7) * 8;
    const int cell_w = (r >> 4)*4 + (c0 >> 4);
    const int slot = (r & 15)*2 + ((c0 >> 3) & 1);
    for (int t = 0; t < 48; ++t) {
      const float* xp = x + ((size_t)bid*48 + t)*4096 + r*64 + c0;
      float4 a = *(const float4*)xp;
      float4 b4 = *(const float4*)(xp+4);
      float sm = a.x+a.y+a.z+a.w + b4.x+b4.y+b4.z+b4.w;
      float mx = fmaxf(fmaxf(fmaxf(a.x,a.y),fmaxf(a.z,a.w)), fmaxf(fmaxf(b4.x,b4.y),fmaxf(b4.z,b4.w)));
      float mn = fminf(fminf(fminf(a.x,a.y),fminf(a.z,a.w)), fminf(fminf(b4.x,b4.y),fminf(b4.z,b4.w)));
      dsum[cell_w*32+slot] = sm; dmax[cell_w*32+slot] = mx; dmin[cell_w*32+slot] = mn;
      __syncthreads();
      if (tid < 256) {
        int cell = tid >> 4, l = tid & 15;
        float s2 = dsum[cell*32+l] + dsum[cell*32+l+16];
        float m2 = fmaxf(dmax[cell*32+l], dmax[cell*32+l+16]);
        float n2 = fminf(dmin[cell*32+l], dmin[cell*32+l+16]);
        #pragma unroll
        for (int m = 8; m >= 1; m >>= 1) {
          s2 += __shfl_xor(s2, m, 16);
          m2 = fmaxf(m2, __shfl_xor(m2, m, 16));
          n2 = fminf(n2, __shfl_xor(n2, m, 16));
        }
        if (l == 0) { cm[cell] = s2*(1.f/256.f); cx[cell] = m2; cnn[cell] = n2; }
      }
      __syncthreads();
      #pragma unroll
      for (int j = 0; j < 2; ++j) {
        int idx = j*512 + tid;
        int cell = idx >> 6, e = idx & 63;
        float v = cm[cell]*Wd[e] + cx[cell]*Wd[64+e] + cnn[cell]*Wd[128+e] + bd[e];
        emb2b[(((size_t)t*16 + cell)*256 + bid)*64 + e] = f2bf(fmaxf(v, 0.f));
      }
      __syncthreads();
    }
  }

  // ---------- prologue B: pack Ws / W_ho into LDS as bf16 B-frags ----------
  __syncthreads();
  for (int s = tid; s < 1024; s += 512) {               // social: wv<4
    int wv = s >> 8, kt = (s >> 6) & 3, ln = s & 63;
    int e = wv*16 + (ln & 15), kb = kt*32 + (ln >> 4)*8;
    const float* src = Ws + (size_t)n*8192 + (size_t)kb*64 + e;
    bf16x8 v;
    #pragma unroll
    for (int j = 0; j < 8; ++j) v[j] = (short)f2bf(src[(size_t)j*64]);
    *(bf16x8*)&sWsF[s*16] = v;
  }
  for (int s = tid; s < 2048; s += 512) {               // head: wv<8
    int wv = s >> 8, kt = (s >> 6) & 3, ln = s & 63;
    int o = wv*16 + (ln & 15), kb = kt*32 + (ln >> 4)*8;
    const float* src = W_ho + (size_t)n*16384 + (size_t)kb*128 + o;
    bf16x8 v;
    #pragma unroll
    for (int j = 0; j < 8; ++j) v[j] = (short)f2bf(src[(size_t)j*128]);
    *(bf16x8*)&sWoF[s*16] = v;
  }

  // ---------- prologue C: resident bf16 gate B-frags + biases ----------
  const int hcol = w*16 + (lane & 15);
  bf16x8 bw[4][8];
  float bias[4];
  {
    const int krow = (lane >> 4)*8;
    #pragma unroll
    for (int G = 0; G < 4; ++G) {
      const float* srcI = W_ih + ((size_t)n*512 + G*128 + hcol)*128;
      const float* srcH = W_hh + ((size_t)n*512 + G*128 + hcol)*128;
      #pragma unroll
      for (int kt = 0; kt < 8; ++kt) {
        const float* s = (kt < 4) ? (srcI + kt*32 + krow) : (srcH + (kt-4)*32 + krow);
        float4 aa = *(const float4*)s;
        float4 bb = *(const float4*)(s+4);
        bf16x8 v;
        v[0]=(short)f2bf(aa.x); v[1]=(short)f2bf(aa.y); v[2]=(short)f2bf(aa.z); v[3]=(short)f2bf(aa.w);
        v[4]=(short)f2bf(bb.x); v[5]=(short)f2bf(bb.y); v[6]=(short)f2bf(bb.z); v[7]=(short)f2bf(bb.w);
        bw[G][kt] = v;
      }
      int gg = n*512 + G*128 + hcol;
      bias[G] = b_ih[gg] + b_hh[gg];
    }
  }
  // zero the h region of sXb (h0 = 0)
  { int b = tid >> 5, j = tid & 31;
    *(uint2*)&sXb[ax(b, 256 + j*8)] = make_uint2(0u, 0u); }

  grid.sync();

  // ---------- per-thread maps ----------
  const int ocol = w*16 + (lane & 15);
  const float bho = b_ho[n*128 + ocol], wout = W_out[ocol];
  const int sb = tid >> 5, sj = tid & 31, se2 = sj*2;
  const float bs0 = bs[se2], bs1 = bs[se2+1];
  float creg[4] = {0.f, 0.f, 0.f, 0.f};
  const int ab = lane & 15, akb = (lane >> 4)*16;

  for (int t = 0; t < 48; ++t) {
    // ---- stage emb (no handshake dependency) ----
    { unsigned v = *(const unsigned*)&emb2b[(((size_t)t*16 + n)*256 + b0c + sb)*64 + se2];
      *(unsigned*)&sXb[ax(sb, sj*4)] = v; }
    __syncthreads();                                     // B1: emb visible (h from prev epilogue)

    // ---- gates partial MFMA: kt {0,1} (emb) + {4..7} (h) — block-local ----
    f32x4 acc[4];
    #pragma unroll
    for (int G = 0; G < 4; ++G) { f32x4 c0 = {bias[G], bias[G], bias[G], bias[G]}; acc[G] = c0; }
    #pragma unroll
    for (int kt = 0; kt < 2; ++kt) {
      bf16x8 aF = *(const bf16x8*)&sXb[ax(ab, kt*64 + akb)];
      #pragma unroll
      for (int G = 0; G < 4; ++G)
        acc[G] = __builtin_amdgcn_mfma_f32_16x16x32_bf16(aF, bw[G][kt], acc[G], 0, 0, 0);
    }
    #pragma unroll
    for (int kt = 4; kt < 8; ++kt) {
      bf16x8 aF = *(const bf16x8*)&sXb[ax(ab, kt*64 + akb)];
      #pragma unroll
      for (int G = 0; G < 4; ++G)
        acc[G] = __builtin_amdgcn_mfma_f32_16x16x32_bf16(aF, bw[G][kt], acc[G], 0, 0, 0);
    }

    // ---- poll previous step's flags: 16 lanes, one padded slot each ----
    if (t > 0 && tid < 16) {
      const int* fp = &flagv[(((t-1)*16 + bt)*16 + tid)*16];
      while (!__hip_atomic_load(fp, __ATOMIC_RELAXED, __HIP_MEMORY_SCOPE_AGENT))
        __builtin_amdgcn_s_sleep(4);
    }
    __syncthreads();                                     // B2: all 16 producers done

    // ---- social reduce (8B sc1 loads) -> relu -> bf16 stage ----
    { float s0 = bs0, s1 = bs1;
      if (t > 0) {
        const unsigned long long* pb = (const unsigned long long*)
          (psoc + (size_t)((t&1)^1)*16*16384 + (size_t)(b0c + sb)*64 + se2);
        #pragma unroll
        for (int nn = 0; nn < 16; ++nn) {
          unsigned long long u = __hip_atomic_load(pb + (size_t)nn*8192, __ATOMIC_RELAXED, __HIP_MEMORY_SCOPE_AGENT);
          float2 f2 = __builtin_bit_cast(float2, u);
          s0 += f2.x; s1 += f2.y;
        }
      }
      unsigned pk = (unsigned)f2bf(fmaxf(s0,0.f)) | ((unsigned)f2bf(fmaxf(s1,0.f)) << 16);
      *(unsigned*)&sXb[ax(sb, 128 + sj*4)] = pk; }
    __syncthreads();                                     // B3: social visible

    // ---- gates MFMA kt {2,3} (social) ----
    #pragma unroll
    for (int kt = 2; kt < 4; ++kt) {
      bf16x8 aF = *(const bf16x8*)&sXb[ax(ab, kt*64 + akb)];
      #pragma unroll
      for (int G = 0; G < 4; ++G)
        acc[G] = __builtin_amdgcn_mfma_f32_16x16x32_bf16(aF, bw[G][kt], acc[G], 0, 0, 0);
    }

    // ---- LSTM cell in registers; write h (bf16) ----
    #pragma unroll
    for (int r = 0; r < 4; ++r) {
      int b = (lane >> 4)*4 + r;
      float cn = sigf(acc[1][r])*creg[r] + sigf(acc[0][r])*tanh_f(acc[2][r]);
      float hn = sigf(acc[3][r])*tanh_f(cn);
      creg[r] = cn;
      *(unsigned short*)&sXb[ax(b, 256 + hcol*2)] = f2bf(hn);
    }
    __syncthreads();                                     // B4: new h visible

    // ---- social (waves 0-3) + head (all waves) via MFMA on bf16 h ----
    f32x4 ph = {bho, bho, bho, bho};
    f32x4 ps = {0.f, 0.f, 0.f, 0.f};
    #pragma unroll
    for (int kt = 0; kt < 4; ++kt) {
      bf16x8 aH = *(const bf16x8*)&sXb[ax(ab, 256 + kt*64 + akb)];
      bf16x8 bo = *(const bf16x8*)&sWoF[((w*4 + kt)*64 + lane)*16];
      ph = __builtin_amdgcn_mfma_f32_16x16x32_bf16(aH, bo, ph, 0, 0, 0);
      if (w < 4) {
        bf16x8 bs_ = *(const bf16x8*)&sWsF[((w*4 + kt)*64 + lane)*16];
        ps = __builtin_amdgcn_mfma_f32_16x16x32_bf16(aH, bs_, ps, 0, 0, 0);
      }
    }
    if (w < 4) {
      const size_t pw = (size_t)(t&1)*16*16384 + (size_t)n*16384;
      const int ecol = w*16 + (lane & 15);
      #pragma unroll
      for (int r = 0; r < 4; ++r) {
        int b = b0c + (lane >> 4)*4 + r;
        __hip_atomic_store(&psoc[pw + (size_t)b*64 + ecol], ps[r], __ATOMIC_RELAXED, __HIP_MEMORY_SCOPE_AGENT);
      }
    }
    asm volatile("s_waitcnt vmcnt(0)" ::: "memory");     // psoc at coherence point
    __syncthreads();                                     // B5: whole block drained
    if (tid == 0)
      __hip_atomic_store(&flagv[((t*16 + bt)*16 + n)*16], 1, __ATOMIC_RELAXED, __HIP_MEMORY_SCOPE_AGENT);

    // ---- head epilogue + y reduce ----
    #pragma unroll
    for (int r = 0; r < 4; ++r) {
      int b = (lane >> 4)*4 + r;
      red[b*132 + ocol] = wout * sigf(ph[r]);
    }
    __syncthreads();                                     // B6
    if (tid < 256) {
      int bb = tid >> 4, l = tid & 15;
      float sm = 0.f;
      #pragma unroll
      for (int kk = 0; kk < 8; ++kk) sm += red[bb*132 + l + 16*kk];
      #pragma unroll
      for (int m = 8; m >= 1; m >>= 1) sm += __shfl_xor(sm, m, 16);
      if (l == 0) y[((size_t)t*256 + b0c + bb)*16 + n] = sm + b_out[0];
    }
  }
}

extern "C" void kernel_launch(void* const* d_in, const int* in_sizes, int n_in,
                              void* d_out, int out_size, void* d_ws, size_t ws_size,
                              hipStream_t stream){
  const float* x    = (const float*)d_in[0];
  const float* Wd   = (const float*)d_in[1];
  const float* bd   = (const float*)d_in[2];
  const float* Ws   = (const float*)d_in[3];
  const float* bs   = (const float*)d_in[4];
  const float* W_ih = (const float*)d_in[5];
  const float* b_ih = (const float*)d_in[6];
  const float* W_hh = (const float*)d_in[7];
  const float* b_hh = (const float*)d_in[8];
  const float* W_ho = (const float*)d_in[9];
  const float* b_ho = (const float*)d_in[10];
  const float* W_out= (const float*)d_in[11];
  const float* b_out= (const float*)d_in[12];
  float* y = (float*)d_out;

  char* ws = (char*)d_ws;
  unsigned short* emb2b = (unsigned short*)ws;          // 25,165,824 B
  float* psoc  = (float*)(ws + 25165824);               // 2,097,152 B (double-buffered)
  int*   flagv = (int*)(ws + 25165824 + 2097152);       // 786,432 B (48*16*16 slots, 64B padded)

  hipFuncSetAttribute((const void*)k_fused, hipFuncAttributeMaxDynamicSharedMemorySize, SMEM_BYTES);

  void* args[] = { (void*)&x, (void*)&Wd, (void*)&bd, (void*)&Ws, (void*)&bs,
                   (void*)&W_ih, (void*)&b_ih, (void*)&W_hh, (void*)&b_hh,
                   (void*)&W_ho, (void*)&b_ho, (void*)&W_out, (void*)&b_out,
                   (void*)&y, (void*)&emb2b, (void*)&psoc, (void*)&flagv };
  hipLaunchCooperativeKernel((const void*)k_fused, dim3(256), dim3(512), args, SMEM_BYTES, stream);
}